// Round 5
// baseline (177.475 us; speedup 1.0000x reference)
//
#include <hip/hip_runtime.h>
#include <math.h>

#define NTH 256

typedef float v4f __attribute__((ext_vector_type(4)));

// ============ workspace float offsets ============
// Final tables (contiguous, staged to LDS by actor_main): 1940 floats = 485 float4
enum : int {
  WQ0_OFF = 0,        // [4][19][8]  = 608
  M_OFF   = 608,      // [36][32]    = 1152   (AO0 @ WQ1fold)
  TB_OFF  = 1760,     // [4][8]      = 32     (B0 @ WQ1fold)
  AO1_OFF = 1792,     // [36][4]     = 144
  B1H_OFF = 1936,     // [4]         = 4
  TBL_N   = 1940,
  // intermediates
  WQ1_OFF = 1952,     // [4][128][8] = 4096
  AO0_OFF = 6048,     // [36][128]   = 4608
  PA0_OFF = 10656,    // [4][7][128] = 3584
  PO0_OFF = 14240,    // [4][2][128] = 1024
  PA1_OFF = 15264,    // 3584
  PO1_OFF = 18848,    // 1024
  F1T_OFF = 19872,    // [128][4] = 512   fpw1_top @ headw
  F1B_OFF = 20384,    // 512              fpw1_bot @ headw
  B0_OFF  = 20896,    // 128
  BB1_OFF = 21024,    // 128
  WS_END  = 21152
};

// ---------------- prep1: everything derivable from raw inputs (wide) ----------------
__global__ void prep1(
    const float* __restrict__ wq0, const float* __restrict__ wak0, const float* __restrict__ wok0,
    const float* __restrict__ wq1, const float* __restrict__ wak1, const float* __restrict__ wok1,
    const float* __restrict__ wav0, const float* __restrict__ apw0,
    const float* __restrict__ wov0, const float* __restrict__ opw0,
    const float* __restrict__ wav1, const float* __restrict__ apw1,
    const float* __restrict__ wov1, const float* __restrict__ opw1,
    const float* __restrict__ fpw1, const float* __restrict__ headw,
    const float* __restrict__ fpw0,
    const float* __restrict__ fpb0, const float* __restrict__ apb0, const float* __restrict__ opb0,
    const float* __restrict__ fpb1, const float* __restrict__ apb1, const float* __restrict__ opb1,
    float* __restrict__ ws)
{
  int gid = blockIdx.x * NTH + threadIdx.x;
  if (gid < 608) {                                      // WQ0[h][r][j]
    int j = gid & 7, r = (gid >> 3) % 19, h = gid / 152;
    const float* a = wq0 + r * 512 + h * 128;
    const float* b = ((j < 6) ? (wak0 + j * 512) : (wok0 + (j - 6) * 512)) + h * 128;
    float acc = 0.f;
    for (int c = 0; c < 128; c++) acc += a[c] * b[c];
    ws[WQ0_OFF + gid] = acc;
  } else if (gid < 4704) {                              // WQ1[h][cc][j]
    int idx = gid - 608;
    int j = idx & 7, cc = (idx >> 3) & 127, h = idx >> 10;
    const float* a = wq1 + cc * 512 + h * 128;
    const float* b = ((j < 6) ? (wak1 + j * 512) : (wok1 + (j - 6) * 512)) + h * 128;
    float acc = 0.f;
    for (int c = 0; c < 128; c++) acc += a[c] * b[c];
    ws[WQ1_OFF + idx] = acc;
  } else if (gid < 8288) {                              // P_a0[h][i][t]
    int idx = gid - 4704;
    int t = idx & 127, i = (idx >> 7) % 7, h = idx / 896;
    const float* w = wav0 + i * 512 + h * 128;
    const float* p = apw0 + (h * 128) * 128 + t;
    float acc = 0.f;
    for (int c = 0; c < 128; c++) acc += w[c] * p[c * 128];
    ws[PA0_OFF + idx] = acc;
  } else if (gid < 9312) {                              // P_o0[h][i][t]
    int idx = gid - 8288;
    int t = idx & 127, i = (idx >> 7) & 1, h = idx >> 8;
    const float* w = wov0 + i * 512 + h * 128;
    const float* p = opw0 + (h * 128) * 128 + t;
    float acc = 0.f;
    for (int c = 0; c < 128; c++) acc += w[c] * p[c * 128];
    ws[PO0_OFF + idx] = acc;
  } else if (gid < 12896) {                             // P_a1
    int idx = gid - 9312;
    int t = idx & 127, i = (idx >> 7) % 7, h = idx / 896;
    const float* w = wav1 + i * 512 + h * 128;
    const float* p = apw1 + (h * 128) * 128 + t;
    float acc = 0.f;
    for (int c = 0; c < 128; c++) acc += w[c] * p[c * 128];
    ws[PA1_OFF + idx] = acc;
  } else if (gid < 13920) {                             // P_o1
    int idx = gid - 12896;
    int t = idx & 127, i = (idx >> 7) & 1, h = idx >> 8;
    const float* w = wov1 + i * 512 + h * 128;
    const float* p = opw1 + (h * 128) * 128 + t;
    float acc = 0.f;
    for (int c = 0; c < 128; c++) acc += w[c] * p[c * 128];
    ws[PO1_OFF + idx] = acc;
  } else if (gid < 14432) {                             // F1T[i][o]
    int idx = gid - 13920;
    int o2 = idx & 3, i = idx >> 2;
    float acc = 0.f;
    for (int j = 0; j < 128; j++) acc += fpw1[i * 128 + j] * headw[j * 4 + o2];
    ws[F1T_OFF + idx] = acc;
  } else if (gid < 14944) {                             // F1B[i][o]
    int idx = gid - 14432;
    int o2 = idx & 3, i = idx >> 2;
    float acc = 0.f;
    for (int j = 0; j < 128; j++) acc += fpw1[(128 + i) * 128 + j] * headw[j * 4 + o2];
    ws[F1B_OFF + idx] = acc;
  } else if (gid < 15072) {                             // B0[j]
    int j = gid - 14944;
    float acc = fpb0[j];
    for (int c = 0; c < 128; c++)
      acc += apb0[c] * fpw0[c * 128 + j] + opb0[c] * fpw0[(128 + c) * 128 + j];
    ws[B0_OFF + j] = acc;
  } else if (gid < 15200) {                             // bb1[j]
    int j = gid - 15072;
    float acc = fpb1[j];
    for (int c = 0; c < 128; c++)
      acc += apb1[c] * fpw1[c * 128 + j] + opb1[c] * fpw1[(128 + c) * 128 + j];
    ws[BB1_OFF + j] = acc;
  }
}

// ---------------- prep2 (wide): AO0, AO1, TB, B1H ----------------
__global__ void prep2(
    const float* __restrict__ fpw0, const float* __restrict__ headw,
    const float* __restrict__ headb, float* __restrict__ ws)
{
  int gid = blockIdx.x * NTH + threadIdx.x;
  if (gid < 4608) {                                     // AO0[h][i][j]  (t = h*9+i)
    int j = gid & 127, i = (gid >> 7) % 9, h = gid / 1152;
    float acc = 0.f;
    if (i < 7) {
      const float* P = ws + PA0_OFF + (h * 7 + i) * 128;
      for (int u = 0; u < 128; u++) acc += P[u] * fpw0[u * 128 + j];
    } else {
      const float* P = ws + PO0_OFF + (h * 2 + (i - 7)) * 128;
      for (int u = 0; u < 128; u++) acc += P[u] * fpw0[(128 + u) * 128 + j];
    }
    ws[AO0_OFF + gid] = acc;
  } else if (gid < 4752) {                              // AO1[h][i][o]
    int idx = gid - 4608;
    int o2 = idx & 3, i = (idx >> 2) % 9, h = idx / 36;
    float acc = 0.f;
    if (i < 7) {
      const float* P = ws + PA1_OFF + (h * 7 + i) * 128;
      for (int u = 0; u < 128; u++) acc += P[u] * ws[F1T_OFF + u * 4 + o2];
    } else {
      const float* P = ws + PO1_OFF + (h * 2 + (i - 7)) * 128;
      for (int u = 0; u < 128; u++) acc += P[u] * ws[F1B_OFF + u * 4 + o2];
    }
    ws[AO1_OFF + idx] = acc;
  } else if (gid < 4784) {                              // TB[h][j]
    int idx = gid - 4752;
    int j = idx & 7, h = idx >> 3;
    float acc = 0.f;
    for (int cc = 0; cc < 128; cc++)
      acc += ws[B0_OFF + cc] * ws[WQ1_OFF + h * 1024 + cc * 8 + j];
    ws[TB_OFF + idx] = acc;
  } else if (gid < 4788) {                              // B1H[o]
    int o2 = gid - 4784;
    float acc = headb[o2];
    for (int j = 0; j < 128; j++) acc += ws[BB1_OFF + j] * headw[j * 4 + o2];
    ws[B1H_OFF + o2] = acc;
  }
}

// ---------------- prep3 (wide): M = AO0 @ WQ1fold ----------------
__global__ void prep3(float* __restrict__ ws)
{
  int gid = blockIdx.x * NTH + threadIdx.x;
  if (gid < 1152) {                                     // M[t][h*8+j]
    int hj = gid & 31, t = gid >> 5;
    int h = hj >> 3, j = hj & 7;
    float acc = 0.f;
    const float* A = ws + AO0_OFF + t * 128;
    const float* W = ws + WQ1_OFF + h * 1024 + j;
    for (int c = 0; c < 128; c++) acc += A[c] * W[c * 8];
    ws[M_OFF + gid] = acc;
  }
}

// ---------------- main: 1 thread/sample; LDS tables; packed v4 math ----------------
__global__ __launch_bounds__(NTH) void actor_main(
    const float* __restrict__ obs, const float* __restrict__ ws,
    const float* __restrict__ pca0, const float* __restrict__ pco0,
    const float* __restrict__ pca1, const float* __restrict__ pco1,
    float* __restrict__ out, int n)
{
  __shared__ v4f stbl[485];             // 1940 floats of folded tables
  const int tid = threadIdx.x;
  const int gid = blockIdx.x * NTH + tid;

  for (int i = tid; i < 485; i += NTH) stbl[i] = ((const v4f*)ws)[i];
  __syncthreads();
  if (gid >= n) return;

  // ---- per-lane obs load (37 contiguous floats) ----
  float o[37];
  {
    const float* op = obs + (size_t)gid * 37;
#pragma unroll
    for (int i = 0; i < 37; i++) o[i] = op[i];
  }
  const float scale = 0.17677669529663687f;   // 1/sqrt(32)

  // ---- unpack features ----
  float qf[19];
#pragma unroll
  for (int i = 0; i < 12; i++) qf[i] = o[i];
#pragma unroll
  for (int i = 0; i < 7; i++) qf[12 + i] = o[30 + i];
  float nb[2][6];
#pragma unroll
  for (int k2 = 0; k2 < 2; k2++)
#pragma unroll
    for (int i = 0; i < 6; i++) nb[k2][i] = o[12 + 6 * k2 + i];
  const float nbv6[2] = { o[24], o[25] };
  const float obf[2][2] = { { o[26], o[27] }, { o[28], o[29] } };
  const float ax = o[0], ay = o[1];

  // ---- distances & decay weights ----
  float dista[2], disto[2];
#pragma unroll
  for (int k2 = 0; k2 < 2; k2++) {
    float dx = ax - nb[k2][0], dy = ay - nb[k2][1];
    dista[k2] = sqrtf(dx * dx + dy * dy);
    float ex = ax - obf[k2][0], ey = ay - obf[k2][1];
    disto[k2] = sqrtf(ex * ex + ey * ey);
  }
  const float ca0 = pca0[0], co0 = pco0[0], ca1 = pca1[0], co1 = pco1[0];
  float dwa0[2], dwo0[2], dwa1[2], dwo1[2];
#pragma unroll
  for (int k2 = 0; k2 < 2; k2++) {
    dwa0[k2] = __expf(-ca0 * dista[k2]);
    dwo0[k2] = __expf(-co0 * disto[k2]);
    dwa1[k2] = __expf(-ca1 * dista[k2]);
    dwo1[k2] = __expf(-co1 * disto[k2]);
  }

  // ---- layer 0 query fold: t0v[h*2+half] (packed) ----
  v4f t0v[8];
#pragma unroll
  for (int z = 0; z < 8; z++) t0v[z] = (v4f)0.f;
#pragma unroll
  for (int h = 0; h < 4; h++) {
#pragma unroll
    for (int r = 0; r < 19; r++) {
      float q = qf[r];
      t0v[h * 2 + 0] += stbl[(h * 19 + r) * 2 + 0] * q;
      t0v[h * 2 + 1] += stbl[(h * 19 + r) * 2 + 1] * q;
    }
  }

  // ---- layer 0 attention -> weighted features wff[36] (t = h*9+i) ----
  float wff[36];
#pragma unroll
  for (int h = 0; h < 4; h++) {
    float la[2], lo[2];
#pragma unroll
    for (int k2 = 0; k2 < 2; k2++) {
      float da = t0v[h*2][0]*nb[k2][0] + t0v[h*2][1]*nb[k2][1] + t0v[h*2][2]*nb[k2][2]
               + t0v[h*2][3]*nb[k2][3] + t0v[h*2+1][0]*nb[k2][4] + t0v[h*2+1][1]*nb[k2][5];
      la[k2] = da * scale * dwa0[k2];
      float dof = t0v[h*2+1][2]*obf[k2][0] + t0v[h*2+1][3]*obf[k2][1];
      lo[k2] = dof * scale * dwo0[k2];
    }
    float e  = __expf(la[1] - la[0]); float aa1 = e  / (1.f + e);  float aa0 = 1.f - aa1;
    float eo = __expf(lo[1] - lo[0]); float bo1 = eo / (1.f + eo); float bo0 = 1.f - bo1;
#pragma unroll
    for (int i = 0; i < 6; i++) wff[h * 9 + i] = aa0 * nb[0][i] + aa1 * nb[1][i];
    wff[h * 9 + 6] = aa0 * nbv6[0] + aa1 * nbv6[1];
    wff[h * 9 + 7] = bo0 * obf[0][0] + bo1 * obf[1][0];
    wff[h * 9 + 8] = bo0 * obf[0][1] + bo1 * obf[1][1];
  }

  // ---- layer 1 query fold via M: t1v = TB + wff @ M (packed) ----
  v4f t1v[8];
#pragma unroll
  for (int q = 0; q < 8; q++) t1v[q] = stbl[440 + q];
#pragma unroll
  for (int t = 0; t < 36; t++) {
    float f = wff[t];
#pragma unroll
    for (int q = 0; q < 8; q++)
      t1v[q] += stbl[152 + t * 8 + q] * f;
  }

  // ---- layer 1 attention ----
  float wf1f[36];
#pragma unroll
  for (int h = 0; h < 4; h++) {
    float la[2], lo[2];
#pragma unroll
    for (int k2 = 0; k2 < 2; k2++) {
      float da = t1v[h*2][0]*nb[k2][0] + t1v[h*2][1]*nb[k2][1] + t1v[h*2][2]*nb[k2][2]
               + t1v[h*2][3]*nb[k2][3] + t1v[h*2+1][0]*nb[k2][4] + t1v[h*2+1][1]*nb[k2][5];
      la[k2] = da * scale * dwa1[k2];
      float dof = t1v[h*2+1][2]*obf[k2][0] + t1v[h*2+1][3]*obf[k2][1];
      lo[k2] = dof * scale * dwo1[k2];
    }
    float e  = __expf(la[1] - la[0]); float aa1 = e  / (1.f + e);  float aa0 = 1.f - aa1;
    float eo = __expf(lo[1] - lo[0]); float bo1 = eo / (1.f + eo); float bo0 = 1.f - bo1;
#pragma unroll
    for (int i = 0; i < 6; i++) wf1f[h * 9 + i] = aa0 * nb[0][i] + aa1 * nb[1][i];
    wf1f[h * 9 + 6] = aa0 * nbv6[0] + aa1 * nbv6[1];
    wf1f[h * 9 + 7] = bo0 * obf[0][0] + bo1 * obf[1][0];
    wf1f[h * 9 + 8] = bo0 * obf[0][1] + bo1 * obf[1][1];
  }

  // ---- output: B1H + wf1f @ AO1 (packed) ----
  v4f acc = stbl[484];
#pragma unroll
  for (int t = 0; t < 36; t++)
    acc += stbl[448 + t] * wf1f[t];
  ((v4f*)out)[gid] = acc;
}

extern "C" void kernel_launch(void* const* d_in, const int* in_sizes, int n_in,
                              void* d_out, int out_size, void* d_ws, size_t ws_size,
                              hipStream_t stream)
{
  const float* obs  = (const float*)d_in[0];
  const float* wq0  = (const float*)d_in[1];
  const float* wak0 = (const float*)d_in[2];
  const float* wav0 = (const float*)d_in[3];
  const float* wok0 = (const float*)d_in[4];
  const float* wov0 = (const float*)d_in[5];
  const float* apw0 = (const float*)d_in[6];
  const float* apb0 = (const float*)d_in[7];
  const float* opw0 = (const float*)d_in[8];
  const float* opb0 = (const float*)d_in[9];
  const float* fpw0 = (const float*)d_in[10];
  const float* fpb0 = (const float*)d_in[11];
  const float* ca0  = (const float*)d_in[12];
  const float* co0  = (const float*)d_in[13];
  const float* wq1  = (const float*)d_in[14];
  const float* wak1 = (const float*)d_in[15];
  const float* wav1 = (const float*)d_in[16];
  const float* wok1 = (const float*)d_in[17];
  const float* wov1 = (const float*)d_in[18];
  const float* apw1 = (const float*)d_in[19];
  const float* apb1 = (const float*)d_in[20];
  const float* opw1 = (const float*)d_in[21];
  const float* opb1 = (const float*)d_in[22];
  const float* fpw1 = (const float*)d_in[23];
  const float* fpb1 = (const float*)d_in[24];
  const float* ca1  = (const float*)d_in[25];
  const float* co1  = (const float*)d_in[26];
  const float* headw = (const float*)d_in[27];
  const float* headb = (const float*)d_in[28];
  float* ws = (float*)d_ws;
  int n = in_sizes[0] / 37;

  prep1<<<(15200 + NTH - 1) / NTH, NTH, 0, stream>>>(
      wq0, wak0, wok0, wq1, wak1, wok1,
      wav0, apw0, wov0, opw0, wav1, apw1, wov1, opw1,
      fpw1, headw, fpw0, fpb0, apb0, opb0, fpb1, apb1, opb1, ws);
  prep2<<<(4788 + NTH - 1) / NTH, NTH, 0, stream>>>(fpw0, headw, headb, ws);
  prep3<<<(1152 + NTH - 1) / NTH, NTH, 0, stream>>>(ws);
  actor_main<<<(n + NTH - 1) / NTH, NTH, 0, stream>>>(
      obs, ws, ca0, co0, ca1, co1, (float*)d_out, n);
}

// Round 6
// 175.220 us; speedup vs baseline: 1.0129x; 1.0129x over previous
//
#include <hip/hip_runtime.h>
#include <math.h>

#define NTH 256

typedef float v4f __attribute__((ext_vector_type(4)));

// ============ workspace float offsets ============
// Final tables (read wave-uniform by actor_main): 1940 floats = 485 float4
enum : int {
  WQ0_OFF = 0,        // [4][19][8]  = 608
  M_OFF   = 608,      // [36][32]    = 1152   (AO0 @ WQ1fold)
  TB_OFF  = 1760,     // [4][8]      = 32     (B0 @ WQ1fold)
  AO1_OFF = 1792,     // [36][4]     = 144
  B1H_OFF = 1936,     // [4]         = 4
  TBL_N   = 1940,
  // intermediates
  WQ1_OFF = 1952,     // [4][128][8] = 4096
  AO0_OFF = 6048,     // [36][128]   = 4608
  PA0_OFF = 10656,    // [4][7][128] = 3584
  PO0_OFF = 14240,    // [4][2][128] = 1024
  PA1_OFF = 15264,    // 3584
  PO1_OFF = 18848,    // 1024
  F1T_OFF = 19872,    // [128][4] = 512   fpw1_top @ headw
  F1B_OFF = 20384,    // 512              fpw1_bot @ headw
  B0_OFF  = 20896,    // 128
  BB1_OFF = 21024,    // 128
  WS_END  = 21152
};

// ---------------- prep1: everything derivable from raw inputs (wide) ----------------
__global__ void prep1(
    const float* __restrict__ wq0, const float* __restrict__ wak0, const float* __restrict__ wok0,
    const float* __restrict__ wq1, const float* __restrict__ wak1, const float* __restrict__ wok1,
    const float* __restrict__ wav0, const float* __restrict__ apw0,
    const float* __restrict__ wov0, const float* __restrict__ opw0,
    const float* __restrict__ wav1, const float* __restrict__ apw1,
    const float* __restrict__ wov1, const float* __restrict__ opw1,
    const float* __restrict__ fpw1, const float* __restrict__ headw,
    const float* __restrict__ fpw0,
    const float* __restrict__ fpb0, const float* __restrict__ apb0, const float* __restrict__ opb0,
    const float* __restrict__ fpb1, const float* __restrict__ apb1, const float* __restrict__ opb1,
    float* __restrict__ ws)
{
  int gid = blockIdx.x * NTH + threadIdx.x;
  if (gid < 608) {                                      // WQ0[h][r][j]
    int j = gid & 7, r = (gid >> 3) % 19, h = gid / 152;
    const float* a = wq0 + r * 512 + h * 128;
    const float* b = ((j < 6) ? (wak0 + j * 512) : (wok0 + (j - 6) * 512)) + h * 128;
    float acc = 0.f;
    for (int c = 0; c < 128; c++) acc += a[c] * b[c];
    ws[WQ0_OFF + gid] = acc;
  } else if (gid < 4704) {                              // WQ1[h][cc][j]
    int idx = gid - 608;
    int j = idx & 7, cc = (idx >> 3) & 127, h = idx >> 10;
    const float* a = wq1 + cc * 512 + h * 128;
    const float* b = ((j < 6) ? (wak1 + j * 512) : (wok1 + (j - 6) * 512)) + h * 128;
    float acc = 0.f;
    for (int c = 0; c < 128; c++) acc += a[c] * b[c];
    ws[WQ1_OFF + idx] = acc;
  } else if (gid < 8288) {                              // P_a0[h][i][t]
    int idx = gid - 4704;
    int t = idx & 127, i = (idx >> 7) % 7, h = idx / 896;
    const float* w = wav0 + i * 512 + h * 128;
    const float* p = apw0 + (h * 128) * 128 + t;
    float acc = 0.f;
    for (int c = 0; c < 128; c++) acc += w[c] * p[c * 128];
    ws[PA0_OFF + idx] = acc;
  } else if (gid < 9312) {                              // P_o0[h][i][t]
    int idx = gid - 8288;
    int t = idx & 127, i = (idx >> 7) & 1, h = idx >> 8;
    const float* w = wov0 + i * 512 + h * 128;
    const float* p = opw0 + (h * 128) * 128 + t;
    float acc = 0.f;
    for (int c = 0; c < 128; c++) acc += w[c] * p[c * 128];
    ws[PO0_OFF + idx] = acc;
  } else if (gid < 12896) {                             // P_a1
    int idx = gid - 9312;
    int t = idx & 127, i = (idx >> 7) % 7, h = idx / 896;
    const float* w = wav1 + i * 512 + h * 128;
    const float* p = apw1 + (h * 128) * 128 + t;
    float acc = 0.f;
    for (int c = 0; c < 128; c++) acc += w[c] * p[c * 128];
    ws[PA1_OFF + idx] = acc;
  } else if (gid < 13920) {                             // P_o1
    int idx = gid - 12896;
    int t = idx & 127, i = (idx >> 7) & 1, h = idx >> 8;
    const float* w = wov1 + i * 512 + h * 128;
    const float* p = opw1 + (h * 128) * 128 + t;
    float acc = 0.f;
    for (int c = 0; c < 128; c++) acc += w[c] * p[c * 128];
    ws[PO1_OFF + idx] = acc;
  } else if (gid < 14432) {                             // F1T[i][o]
    int idx = gid - 13920;
    int o2 = idx & 3, i = idx >> 2;
    float acc = 0.f;
    for (int j = 0; j < 128; j++) acc += fpw1[i * 128 + j] * headw[j * 4 + o2];
    ws[F1T_OFF + idx] = acc;
  } else if (gid < 14944) {                             // F1B[i][o]
    int idx = gid - 14432;
    int o2 = idx & 3, i = idx >> 2;
    float acc = 0.f;
    for (int j = 0; j < 128; j++) acc += fpw1[(128 + i) * 128 + j] * headw[j * 4 + o2];
    ws[F1B_OFF + idx] = acc;
  } else if (gid < 15072) {                             // B0[j]
    int j = gid - 14944;
    float acc = fpb0[j];
    for (int c = 0; c < 128; c++)
      acc += apb0[c] * fpw0[c * 128 + j] + opb0[c] * fpw0[(128 + c) * 128 + j];
    ws[B0_OFF + j] = acc;
  } else if (gid < 15200) {                             // bb1[j]
    int j = gid - 15072;
    float acc = fpb1[j];
    for (int c = 0; c < 128; c++)
      acc += apb1[c] * fpw1[c * 128 + j] + opb1[c] * fpw1[(128 + c) * 128 + j];
    ws[BB1_OFF + j] = acc;
  }
}

// ---------------- prep2 (wide): AO0, AO1, TB, B1H ----------------
__global__ void prep2(
    const float* __restrict__ fpw0, const float* __restrict__ headw,
    const float* __restrict__ headb, float* __restrict__ ws)
{
  int gid = blockIdx.x * NTH + threadIdx.x;
  if (gid < 4608) {                                     // AO0[h][i][j]  (t = h*9+i)
    int j = gid & 127, i = (gid >> 7) % 9, h = gid / 1152;
    float acc = 0.f;
    if (i < 7) {
      const float* P = ws + PA0_OFF + (h * 7 + i) * 128;
      for (int u = 0; u < 128; u++) acc += P[u] * fpw0[u * 128 + j];
    } else {
      const float* P = ws + PO0_OFF + (h * 2 + (i - 7)) * 128;
      for (int u = 0; u < 128; u++) acc += P[u] * fpw0[(128 + u) * 128 + j];
    }
    ws[AO0_OFF + gid] = acc;
  } else if (gid < 4752) {                              // AO1[h][i][o]
    int idx = gid - 4608;
    int o2 = idx & 3, i = (idx >> 2) % 9, h = idx / 36;
    float acc = 0.f;
    if (i < 7) {
      const float* P = ws + PA1_OFF + (h * 7 + i) * 128;
      for (int u = 0; u < 128; u++) acc += P[u] * ws[F1T_OFF + u * 4 + o2];
    } else {
      const float* P = ws + PO1_OFF + (h * 2 + (i - 7)) * 128;
      for (int u = 0; u < 128; u++) acc += P[u] * ws[F1B_OFF + u * 4 + o2];
    }
    ws[AO1_OFF + idx] = acc;
  } else if (gid < 4784) {                              // TB[h][j]
    int idx = gid - 4752;
    int j = idx & 7, h = idx >> 3;
    float acc = 0.f;
    for (int cc = 0; cc < 128; cc++)
      acc += ws[B0_OFF + cc] * ws[WQ1_OFF + h * 1024 + cc * 8 + j];
    ws[TB_OFF + idx] = acc;
  } else if (gid < 4788) {                              // B1H[o]
    int o2 = gid - 4784;
    float acc = headb[o2];
    for (int j = 0; j < 128; j++) acc += ws[BB1_OFF + j] * headw[j * 4 + o2];
    ws[B1H_OFF + o2] = acc;
  }
}

// ---------------- prep3 (wide): M = AO0 @ WQ1fold ----------------
__global__ void prep3(float* __restrict__ ws)
{
  int gid = blockIdx.x * NTH + threadIdx.x;
  if (gid < 1152) {                                     // M[t][h*8+j]
    int hj = gid & 31, t = gid >> 5;
    int h = hj >> 3, j = hj & 7;
    float acc = 0.f;
    const float* A = ws + AO0_OFF + t * 128;
    const float* W = ws + WQ1_OFF + h * 1024 + j;
    for (int c = 0; c < 128; c++) acc += A[c] * W[c * 8];
    ws[M_OFF + gid] = acc;
  }
}

// ---------------- main: 1 thread/sample; wave-uniform table reads (scalar pipe) ----------------
__global__ __launch_bounds__(NTH) void actor_main(
    const float* __restrict__ obs, const float* __restrict__ ws,
    const float* __restrict__ pca0, const float* __restrict__ pco0,
    const float* __restrict__ pca1, const float* __restrict__ pco1,
    float* __restrict__ out, int n)
{
  const int gid = blockIdx.x * NTH + threadIdx.x;
  if (gid >= n) return;

  // All tbl[] indices below are compile-time constants -> wave-uniform
  // addresses -> compiler emits s_load (scalar pipe), not LDS/vector loads.
  const v4f* __restrict__ tbl = (const v4f*)ws;

  // ---- per-lane obs load (37 contiguous floats) ----
  float o[37];
  {
    const float* op = obs + (size_t)gid * 37;
#pragma unroll
    for (int i = 0; i < 37; i++) o[i] = op[i];
  }
  const float scale = 0.17677669529663687f;   // 1/sqrt(32)

  // ---- unpack features ----
  float qf[19];
#pragma unroll
  for (int i = 0; i < 12; i++) qf[i] = o[i];
#pragma unroll
  for (int i = 0; i < 7; i++) qf[12 + i] = o[30 + i];
  float nb[2][6];
#pragma unroll
  for (int k2 = 0; k2 < 2; k2++)
#pragma unroll
    for (int i = 0; i < 6; i++) nb[k2][i] = o[12 + 6 * k2 + i];
  const float nbv6[2] = { o[24], o[25] };
  const float obf[2][2] = { { o[26], o[27] }, { o[28], o[29] } };
  const float ax = o[0], ay = o[1];

  // ---- distances & decay weights ----
  float dista[2], disto[2];
#pragma unroll
  for (int k2 = 0; k2 < 2; k2++) {
    float dx = ax - nb[k2][0], dy = ay - nb[k2][1];
    dista[k2] = sqrtf(dx * dx + dy * dy);
    float ex = ax - obf[k2][0], ey = ay - obf[k2][1];
    disto[k2] = sqrtf(ex * ex + ey * ey);
  }
  const float ca0 = pca0[0], co0 = pco0[0], ca1 = pca1[0], co1 = pco1[0];
  float dwa0[2], dwo0[2], dwa1[2], dwo1[2];
#pragma unroll
  for (int k2 = 0; k2 < 2; k2++) {
    dwa0[k2] = __expf(-ca0 * dista[k2]);
    dwo0[k2] = __expf(-co0 * disto[k2]);
    dwa1[k2] = __expf(-ca1 * dista[k2]);
    dwo1[k2] = __expf(-co1 * disto[k2]);
  }

  // ---- layer 0 query fold: t0v[h*2+half] (packed) ----
  v4f t0v[8];
#pragma unroll
  for (int z = 0; z < 8; z++) t0v[z] = (v4f)0.f;
#pragma unroll
  for (int h = 0; h < 4; h++) {
#pragma unroll
    for (int r = 0; r < 19; r++) {
      float q = qf[r];
      t0v[h * 2 + 0] += tbl[(h * 19 + r) * 2 + 0] * q;
      t0v[h * 2 + 1] += tbl[(h * 19 + r) * 2 + 1] * q;
    }
  }

  // ---- layer 0 attention -> weighted features wff[36] (t = h*9+i) ----
  float wff[36];
#pragma unroll
  for (int h = 0; h < 4; h++) {
    float la[2], lo[2];
#pragma unroll
    for (int k2 = 0; k2 < 2; k2++) {
      float da = t0v[h*2][0]*nb[k2][0] + t0v[h*2][1]*nb[k2][1] + t0v[h*2][2]*nb[k2][2]
               + t0v[h*2][3]*nb[k2][3] + t0v[h*2+1][0]*nb[k2][4] + t0v[h*2+1][1]*nb[k2][5];
      la[k2] = da * scale * dwa0[k2];
      float dof = t0v[h*2+1][2]*obf[k2][0] + t0v[h*2+1][3]*obf[k2][1];
      lo[k2] = dof * scale * dwo0[k2];
    }
    float e  = __expf(la[1] - la[0]); float aa1 = e  / (1.f + e);  float aa0 = 1.f - aa1;
    float eo = __expf(lo[1] - lo[0]); float bo1 = eo / (1.f + eo); float bo0 = 1.f - bo1;
#pragma unroll
    for (int i = 0; i < 6; i++) wff[h * 9 + i] = aa0 * nb[0][i] + aa1 * nb[1][i];
    wff[h * 9 + 6] = aa0 * nbv6[0] + aa1 * nbv6[1];
    wff[h * 9 + 7] = bo0 * obf[0][0] + bo1 * obf[1][0];
    wff[h * 9 + 8] = bo0 * obf[0][1] + bo1 * obf[1][1];
  }

  // ---- layer 1 query fold via M: t1v = TB + wff @ M (packed) ----
  v4f t1v[8];
#pragma unroll
  for (int q = 0; q < 8; q++) t1v[q] = tbl[440 + q];
#pragma unroll
  for (int t = 0; t < 36; t++) {
    float f = wff[t];
#pragma unroll
    for (int q = 0; q < 8; q++)
      t1v[q] += tbl[152 + t * 8 + q] * f;
  }

  // ---- layer 1 attention ----
  float wf1f[36];
#pragma unroll
  for (int h = 0; h < 4; h++) {
    float la[2], lo[2];
#pragma unroll
    for (int k2 = 0; k2 < 2; k2++) {
      float da = t1v[h*2][0]*nb[k2][0] + t1v[h*2][1]*nb[k2][1] + t1v[h*2][2]*nb[k2][2]
               + t1v[h*2][3]*nb[k2][3] + t1v[h*2+1][0]*nb[k2][4] + t1v[h*2+1][1]*nb[k2][5];
      la[k2] = da * scale * dwa1[k2];
      float dof = t1v[h*2+1][2]*obf[k2][0] + t1v[h*2+1][3]*obf[k2][1];
      lo[k2] = dof * scale * dwo1[k2];
    }
    float e  = __expf(la[1] - la[0]); float aa1 = e  / (1.f + e);  float aa0 = 1.f - aa1;
    float eo = __expf(lo[1] - lo[0]); float bo1 = eo / (1.f + eo); float bo0 = 1.f - bo1;
#pragma unroll
    for (int i = 0; i < 6; i++) wf1f[h * 9 + i] = aa0 * nb[0][i] + aa1 * nb[1][i];
    wf1f[h * 9 + 6] = aa0 * nbv6[0] + aa1 * nbv6[1];
    wf1f[h * 9 + 7] = bo0 * obf[0][0] + bo1 * obf[1][0];
    wf1f[h * 9 + 8] = bo0 * obf[0][1] + bo1 * obf[1][1];
  }

  // ---- output: B1H + wf1f @ AO1 (packed) ----
  v4f acc = tbl[484];
#pragma unroll
  for (int t = 0; t < 36; t++)
    acc += tbl[448 + t] * wf1f[t];
  ((v4f*)out)[gid] = acc;
}

extern "C" void kernel_launch(void* const* d_in, const int* in_sizes, int n_in,
                              void* d_out, int out_size, void* d_ws, size_t ws_size,
                              hipStream_t stream)
{
  const float* obs  = (const float*)d_in[0];
  const float* wq0  = (const float*)d_in[1];
  const float* wak0 = (const float*)d_in[2];
  const float* wav0 = (const float*)d_in[3];
  const float* wok0 = (const float*)d_in[4];
  const float* wov0 = (const float*)d_in[5];
  const float* apw0 = (const float*)d_in[6];
  const float* apb0 = (const float*)d_in[7];
  const float* opw0 = (const float*)d_in[8];
  const float* opb0 = (const float*)d_in[9];
  const float* fpw0 = (const float*)d_in[10];
  const float* fpb0 = (const float*)d_in[11];
  const float* ca0  = (const float*)d_in[12];
  const float* co0  = (const float*)d_in[13];
  const float* wq1  = (const float*)d_in[14];
  const float* wak1 = (const float*)d_in[15];
  const float* wav1 = (const float*)d_in[16];
  const float* wok1 = (const float*)d_in[17];
  const float* wov1 = (const float*)d_in[18];
  const float* apw1 = (const float*)d_in[19];
  const float* apb1 = (const float*)d_in[20];
  const float* opw1 = (const float*)d_in[21];
  const float* opb1 = (const float*)d_in[22];
  const float* fpw1 = (const float*)d_in[23];
  const float* fpb1 = (const float*)d_in[24];
  const float* ca1  = (const float*)d_in[25];
  const float* co1  = (const float*)d_in[26];
  const float* headw = (const float*)d_in[27];
  const float* headb = (const float*)d_in[28];
  float* ws = (float*)d_ws;
  int n = in_sizes[0] / 37;

  prep1<<<(15200 + NTH - 1) / NTH, NTH, 0, stream>>>(
      wq0, wak0, wok0, wq1, wak1, wok1,
      wav0, apw0, wov0, opw0, wav1, apw1, wov1, opw1,
      fpw1, headw, fpw0, fpb0, apb0, opb0, fpb1, apb1, opb1, ws);
  prep2<<<(4788 + NTH - 1) / NTH, NTH, 0, stream>>>(fpw0, headw, headb, ws);
  prep3<<<(1152 + NTH - 1) / NTH, NTH, 0, stream>>>(ws);
  actor_main<<<(n + NTH - 1) / NTH, NTH, 0, stream>>>(
      obs, ws, ca0, co0, ca1, co1, (float*)d_out, n);
}

// Round 7
// 169.416 us; speedup vs baseline: 1.0476x; 1.0343x over previous
//
#include <hip/hip_runtime.h>
#include <math.h>

#define NTH 256

typedef float v4f __attribute__((ext_vector_type(4)));

// ============ workspace float offsets ============
// Final tables (read wave-uniform by actor_main): 1940 floats = 485 float4
enum : int {
  WQ0_OFF = 0,        // [4][19][8]  = 608
  M_OFF   = 608,      // [36][32]    = 1152   (AO0 @ WQ1fold)
  TB_OFF  = 1760,     // [4][8]      = 32     (B0 @ WQ1fold)
  AO1_OFF = 1792,     // [36][4]     = 144
  B1H_OFF = 1936,     // [4]         = 4
  TBL_N   = 1940,
  // intermediates (prep1 -> prep_late)
  WQ1_OFF = 1952,     // [4][128][8] = 4096
  PA0_OFF = 6048,     // [4][7][128] = 3584
  PO0_OFF = 9632,     // [4][2][128] = 1024
  PA1_OFF = 10656,    // 3584
  PO1_OFF = 14240,    // 1024
  F1T_OFF = 15264,    // [128][4] = 512   fpw1_top @ headw
  F1B_OFF = 15776,    // 512              fpw1_bot @ headw
  B0_OFF  = 16288,    // 128
  BB1_OFF = 16416,    // 128
  WS_END  = 16544
};

// ---------------- prep1: everything derivable from raw inputs (wide) ----------------
__global__ void prep1(
    const float* __restrict__ wq0, const float* __restrict__ wak0, const float* __restrict__ wok0,
    const float* __restrict__ wq1, const float* __restrict__ wak1, const float* __restrict__ wok1,
    const float* __restrict__ wav0, const float* __restrict__ apw0,
    const float* __restrict__ wov0, const float* __restrict__ opw0,
    const float* __restrict__ wav1, const float* __restrict__ apw1,
    const float* __restrict__ wov1, const float* __restrict__ opw1,
    const float* __restrict__ fpw1, const float* __restrict__ headw,
    const float* __restrict__ fpw0,
    const float* __restrict__ fpb0, const float* __restrict__ apb0, const float* __restrict__ opb0,
    const float* __restrict__ fpb1, const float* __restrict__ apb1, const float* __restrict__ opb1,
    float* __restrict__ ws)
{
  int gid = blockIdx.x * NTH + threadIdx.x;
  if (gid < 608) {                                      // WQ0[h][r][j]
    int j = gid & 7, r = (gid >> 3) % 19, h = gid / 152;
    const float* a = wq0 + r * 512 + h * 128;
    const float* b = ((j < 6) ? (wak0 + j * 512) : (wok0 + (j - 6) * 512)) + h * 128;
    float acc = 0.f;
    for (int c = 0; c < 128; c++) acc += a[c] * b[c];
    ws[WQ0_OFF + gid] = acc;
  } else if (gid < 4704) {                              // WQ1[h][cc][j]
    int idx = gid - 608;
    int j = idx & 7, cc = (idx >> 3) & 127, h = idx >> 10;
    const float* a = wq1 + cc * 512 + h * 128;
    const float* b = ((j < 6) ? (wak1 + j * 512) : (wok1 + (j - 6) * 512)) + h * 128;
    float acc = 0.f;
    for (int c = 0; c < 128; c++) acc += a[c] * b[c];
    ws[WQ1_OFF + idx] = acc;
  } else if (gid < 8288) {                              // P_a0[h][i][t]
    int idx = gid - 4704;
    int t = idx & 127, i = (idx >> 7) % 7, h = idx / 896;
    const float* w = wav0 + i * 512 + h * 128;
    const float* p = apw0 + (h * 128) * 128 + t;
    float acc = 0.f;
    for (int c = 0; c < 128; c++) acc += w[c] * p[c * 128];
    ws[PA0_OFF + idx] = acc;
  } else if (gid < 9312) {                              // P_o0[h][i][t]
    int idx = gid - 8288;
    int t = idx & 127, i = (idx >> 7) & 1, h = idx >> 8;
    const float* w = wov0 + i * 512 + h * 128;
    const float* p = opw0 + (h * 128) * 128 + t;
    float acc = 0.f;
    for (int c = 0; c < 128; c++) acc += w[c] * p[c * 128];
    ws[PO0_OFF + idx] = acc;
  } else if (gid < 12896) {                             // P_a1
    int idx = gid - 9312;
    int t = idx & 127, i = (idx >> 7) % 7, h = idx / 896;
    const float* w = wav1 + i * 512 + h * 128;
    const float* p = apw1 + (h * 128) * 128 + t;
    float acc = 0.f;
    for (int c = 0; c < 128; c++) acc += w[c] * p[c * 128];
    ws[PA1_OFF + idx] = acc;
  } else if (gid < 13920) {                             // P_o1
    int idx = gid - 12896;
    int t = idx & 127, i = (idx >> 7) & 1, h = idx >> 8;
    const float* w = wov1 + i * 512 + h * 128;
    const float* p = opw1 + (h * 128) * 128 + t;
    float acc = 0.f;
    for (int c = 0; c < 128; c++) acc += w[c] * p[c * 128];
    ws[PO1_OFF + idx] = acc;
  } else if (gid < 14432) {                             // F1T[i][o]
    int idx = gid - 13920;
    int o2 = idx & 3, i = idx >> 2;
    float acc = 0.f;
    for (int j = 0; j < 128; j++) acc += fpw1[i * 128 + j] * headw[j * 4 + o2];
    ws[F1T_OFF + idx] = acc;
  } else if (gid < 14944) {                             // F1B[i][o]
    int idx = gid - 14432;
    int o2 = idx & 3, i = idx >> 2;
    float acc = 0.f;
    for (int j = 0; j < 128; j++) acc += fpw1[(128 + i) * 128 + j] * headw[j * 4 + o2];
    ws[F1B_OFF + idx] = acc;
  } else if (gid < 15072) {                             // B0[j]
    int j = gid - 14944;
    float acc = fpb0[j];
    for (int c = 0; c < 128; c++)
      acc += apb0[c] * fpw0[c * 128 + j] + opb0[c] * fpw0[(128 + c) * 128 + j];
    ws[B0_OFF + j] = acc;
  } else if (gid < 15200) {                             // bb1[j]
    int j = gid - 15072;
    float acc = fpb1[j];
    for (int c = 0; c < 128; c++)
      acc += apb1[c] * fpw1[c * 128 + j] + opb1[c] * fpw1[(128 + c) * 128 + j];
    ws[BB1_OFF + j] = acc;
  }
}

// ---------------- prep_late: fused prep2+prep3 ----------------
// Blocks 0..35: block t computes AO0 row t (128 dots) into LDS, then M[t][0..32).
// Block 36: AO1 (144), TB (32), B1H (4).  AO0 never touches global memory.
__global__ __launch_bounds__(NTH) void prep_late(
    const float* __restrict__ fpw0, const float* __restrict__ headw,
    const float* __restrict__ headb, float* __restrict__ ws)
{
  const int b = blockIdx.x;
  const int tid = threadIdx.x;
  if (b < 36) {
    __shared__ float sAO0[128];
    const int t = b, h = t / 9, i = t % 9;
    if (tid < 128) {
      float acc = 0.f;
      if (i < 7) {
        const float* P = ws + PA0_OFF + (h * 7 + i) * 128;
        for (int u = 0; u < 128; u++) acc += P[u] * fpw0[u * 128 + tid];
      } else {
        const float* P = ws + PO0_OFF + (h * 2 + (i - 7)) * 128;
        for (int u = 0; u < 128; u++) acc += P[u] * fpw0[(128 + u) * 128 + tid];
      }
      sAO0[tid] = acc;
    }
    __syncthreads();
    if (tid < 32) {                                     // M[t][h2*8+j2]
      const int h2 = tid >> 3, j2 = tid & 7;
      float acc = 0.f;
      const float* W = ws + WQ1_OFF + h2 * 1024 + j2;
      for (int c = 0; c < 128; c++) acc += sAO0[c] * W[c * 8];
      ws[M_OFF + t * 32 + tid] = acc;
    }
  } else {
    if (tid < 144) {                                    // AO1[h][i][o]
      const int o2 = tid & 3, i = (tid >> 2) % 9, h = tid / 36;
      float acc = 0.f;
      if (i < 7) {
        const float* P = ws + PA1_OFF + (h * 7 + i) * 128;
        for (int u = 0; u < 128; u++) acc += P[u] * ws[F1T_OFF + u * 4 + o2];
      } else {
        const float* P = ws + PO1_OFF + (h * 2 + (i - 7)) * 128;
        for (int u = 0; u < 128; u++) acc += P[u] * ws[F1B_OFF + u * 4 + o2];
      }
      ws[AO1_OFF + tid] = acc;
    } else if (tid < 176) {                             // TB[h][j]
      const int idx = tid - 144;
      const int j = idx & 7, h = idx >> 3;
      float acc = 0.f;
      for (int cc = 0; cc < 128; cc++)
        acc += ws[B0_OFF + cc] * ws[WQ1_OFF + h * 1024 + cc * 8 + j];
      ws[TB_OFF + idx] = acc;
    } else if (tid < 180) {                             // B1H[o]
      const int o2 = tid - 176;
      float acc = headb[o2];
      for (int j = 0; j < 128; j++) acc += ws[BB1_OFF + j] * headw[j * 4 + o2];
      ws[B1H_OFF + o2] = acc;
    }
  }
}

// ---------------- main: 1 thread/sample; wave-uniform table reads (scalar pipe) ----------------
__global__ __launch_bounds__(NTH) void actor_main(
    const float* __restrict__ obs, const float* __restrict__ ws,
    const float* __restrict__ pca0, const float* __restrict__ pco0,
    const float* __restrict__ pca1, const float* __restrict__ pco1,
    float* __restrict__ out, int n)
{
  const int gid = blockIdx.x * NTH + threadIdx.x;
  if (gid >= n) return;

  // All tbl[] indices below are compile-time constants -> wave-uniform
  // addresses -> scalar-pipe s_load; table (7.8 KB) stays L1/K$-resident.
  const v4f* __restrict__ tbl = (const v4f*)ws;

  // ---- per-lane obs load (37 contiguous floats) ----
  float o[37];
  {
    const float* op = obs + (size_t)gid * 37;
#pragma unroll
    for (int i = 0; i < 37; i++) o[i] = op[i];
  }
  const float scale = 0.17677669529663687f;   // 1/sqrt(32)

  // ---- unpack features ----
  float qf[19];
#pragma unroll
  for (int i = 0; i < 12; i++) qf[i] = o[i];
#pragma unroll
  for (int i = 0; i < 7; i++) qf[12 + i] = o[30 + i];
  float nb[2][6];
#pragma unroll
  for (int k2 = 0; k2 < 2; k2++)
#pragma unroll
    for (int i = 0; i < 6; i++) nb[k2][i] = o[12 + 6 * k2 + i];
  const float nbv6[2] = { o[24], o[25] };
  const float obf[2][2] = { { o[26], o[27] }, { o[28], o[29] } };
  const float ax = o[0], ay = o[1];

  // ---- distances & decay weights ----
  float dista[2], disto[2];
#pragma unroll
  for (int k2 = 0; k2 < 2; k2++) {
    float dx = ax - nb[k2][0], dy = ay - nb[k2][1];
    dista[k2] = sqrtf(dx * dx + dy * dy);
    float ex = ax - obf[k2][0], ey = ay - obf[k2][1];
    disto[k2] = sqrtf(ex * ex + ey * ey);
  }
  const float ca0 = pca0[0], co0 = pco0[0], ca1 = pca1[0], co1 = pco1[0];
  float dwa0[2], dwo0[2], dwa1[2], dwo1[2];
#pragma unroll
  for (int k2 = 0; k2 < 2; k2++) {
    dwa0[k2] = __expf(-ca0 * dista[k2]);
    dwo0[k2] = __expf(-co0 * disto[k2]);
    dwa1[k2] = __expf(-ca1 * dista[k2]);
    dwo1[k2] = __expf(-co1 * disto[k2]);
  }

  // ---- layer 0 query fold: t0v[h*2+half] (packed) ----
  v4f t0v[8];
#pragma unroll
  for (int z = 0; z < 8; z++) t0v[z] = (v4f)0.f;
#pragma unroll
  for (int h = 0; h < 4; h++) {
#pragma unroll
    for (int r = 0; r < 19; r++) {
      float q = qf[r];
      t0v[h * 2 + 0] += tbl[(h * 19 + r) * 2 + 0] * q;
      t0v[h * 2 + 1] += tbl[(h * 19 + r) * 2 + 1] * q;
    }
  }

  // ---- layer 0 attention -> weighted features wff[36] (t = h*9+i) ----
  float wff[36];
#pragma unroll
  for (int h = 0; h < 4; h++) {
    float la[2], lo[2];
#pragma unroll
    for (int k2 = 0; k2 < 2; k2++) {
      float da = t0v[h*2][0]*nb[k2][0] + t0v[h*2][1]*nb[k2][1] + t0v[h*2][2]*nb[k2][2]
               + t0v[h*2][3]*nb[k2][3] + t0v[h*2+1][0]*nb[k2][4] + t0v[h*2+1][1]*nb[k2][5];
      la[k2] = da * scale * dwa0[k2];
      float dof = t0v[h*2+1][2]*obf[k2][0] + t0v[h*2+1][3]*obf[k2][1];
      lo[k2] = dof * scale * dwo0[k2];
    }
    float e  = __expf(la[1] - la[0]); float aa1 = e  / (1.f + e);  float aa0 = 1.f - aa1;
    float eo = __expf(lo[1] - lo[0]); float bo1 = eo / (1.f + eo); float bo0 = 1.f - bo1;
#pragma unroll
    for (int i = 0; i < 6; i++) wff[h * 9 + i] = aa0 * nb[0][i] + aa1 * nb[1][i];
    wff[h * 9 + 6] = aa0 * nbv6[0] + aa1 * nbv6[1];
    wff[h * 9 + 7] = bo0 * obf[0][0] + bo1 * obf[1][0];
    wff[h * 9 + 8] = bo0 * obf[0][1] + bo1 * obf[1][1];
  }

  // ---- layer 1 query fold via M: t1v = TB + wff @ M (packed) ----
  v4f t1v[8];
#pragma unroll
  for (int q = 0; q < 8; q++) t1v[q] = tbl[440 + q];
#pragma unroll
  for (int t = 0; t < 36; t++) {
    float f = wff[t];
#pragma unroll
    for (int q = 0; q < 8; q++)
      t1v[q] += tbl[152 + t * 8 + q] * f;
  }

  // ---- layer 1 attention ----
  float wf1f[36];
#pragma unroll
  for (int h = 0; h < 4; h++) {
    float la[2], lo[2];
#pragma unroll
    for (int k2 = 0; k2 < 2; k2++) {
      float da = t1v[h*2][0]*nb[k2][0] + t1v[h*2][1]*nb[k2][1] + t1v[h*2][2]*nb[k2][2]
               + t1v[h*2][3]*nb[k2][3] + t1v[h*2+1][0]*nb[k2][4] + t1v[h*2+1][1]*nb[k2][5];
      la[k2] = da * scale * dwa1[k2];
      float dof = t1v[h*2+1][2]*obf[k2][0] + t1v[h*2+1][3]*obf[k2][1];
      lo[k2] = dof * scale * dwo1[k2];
    }
    float e  = __expf(la[1] - la[0]); float aa1 = e  / (1.f + e);  float aa0 = 1.f - aa1;
    float eo = __expf(lo[1] - lo[0]); float bo1 = eo / (1.f + eo); float bo0 = 1.f - bo1;
#pragma unroll
    for (int i = 0; i < 6; i++) wf1f[h * 9 + i] = aa0 * nb[0][i] + aa1 * nb[1][i];
    wf1f[h * 9 + 6] = aa0 * nbv6[0] + aa1 * nbv6[1];
    wf1f[h * 9 + 7] = bo0 * obf[0][0] + bo1 * obf[1][0];
    wf1f[h * 9 + 8] = bo0 * obf[0][1] + bo1 * obf[1][1];
  }

  // ---- output: B1H + wf1f @ AO1 (packed) ----
  v4f acc = tbl[484];
#pragma unroll
  for (int t = 0; t < 36; t++)
    acc += tbl[448 + t] * wf1f[t];
  ((v4f*)out)[gid] = acc;
}

extern "C" void kernel_launch(void* const* d_in, const int* in_sizes, int n_in,
                              void* d_out, int out_size, void* d_ws, size_t ws_size,
                              hipStream_t stream)
{
  const float* obs  = (const float*)d_in[0];
  const float* wq0  = (const float*)d_in[1];
  const float* wak0 = (const float*)d_in[2];
  const float* wav0 = (const float*)d_in[3];
  const float* wok0 = (const float*)d_in[4];
  const float* wov0 = (const float*)d_in[5];
  const float* apw0 = (const float*)d_in[6];
  const float* apb0 = (const float*)d_in[7];
  const float* opw0 = (const float*)d_in[8];
  const float* opb0 = (const float*)d_in[9];
  const float* fpw0 = (const float*)d_in[10];
  const float* fpb0 = (const float*)d_in[11];
  const float* ca0  = (const float*)d_in[12];
  const float* co0  = (const float*)d_in[13];
  const float* wq1  = (const float*)d_in[14];
  const float* wak1 = (const float*)d_in[15];
  const float* wav1 = (const float*)d_in[16];
  const float* wok1 = (const float*)d_in[17];
  const float* wov1 = (const float*)d_in[18];
  const float* apw1 = (const float*)d_in[19];
  const float* apb1 = (const float*)d_in[20];
  const float* opw1 = (const float*)d_in[21];
  const float* opb1 = (const float*)d_in[22];
  const float* fpw1 = (const float*)d_in[23];
  const float* fpb1 = (const float*)d_in[24];
  const float* ca1  = (const float*)d_in[25];
  const float* co1  = (const float*)d_in[26];
  const float* headw = (const float*)d_in[27];
  const float* headb = (const float*)d_in[28];
  float* ws = (float*)d_ws;
  int n = in_sizes[0] / 37;

  prep1<<<(15200 + NTH - 1) / NTH, NTH, 0, stream>>>(
      wq0, wak0, wok0, wq1, wak1, wok1,
      wav0, apw0, wov0, opw0, wav1, apw1, wov1, opw1,
      fpw1, headw, fpw0, fpb0, apb0, opb0, fpb1, apb1, opb1, ws);
  prep_late<<<37, NTH, 0, stream>>>(fpw0, headw, headb, ws);
  actor_main<<<(n + NTH - 1) / NTH, NTH, 0, stream>>>(
      obs, ws, ca0, co0, ca1, co1, (float*)d_out, n);
}

// Round 9
// 167.731 us; speedup vs baseline: 1.0581x; 1.0100x over previous
//
#include <hip/hip_runtime.h>
#include <math.h>

#define NTH 256

typedef float v4f __attribute__((ext_vector_type(4)));

// ============ workspace float offsets ============
// Final tables (read wave-uniform by actor_main): 1940 floats = 485 float4
enum : int {
  WQ0_OFF = 0,        // [4][19][8]  = 608
  M_OFF   = 608,      // [36][32]    = 1152   (AO0 @ WQ1fold)
  TB_OFF  = 1760,     // [4][8]      = 32     (B0 @ WQ1fold)
  AO1_OFF = 1792,     // [36][4]     = 144
  B1H_OFF = 1936,     // [4]         = 4
  TBL_N   = 1940,
  // intermediates (prep1 -> prep_late)
  WQ1_OFF = 1952,     // [4][128][8] = 4096
  PA0_OFF = 6048,     // [4][7][128] = 3584
  PO0_OFF = 9632,     // [4][2][128] = 1024
  PA1_OFF = 10656,    // 3584
  PO1_OFF = 14240,    // 1024
  F1T_OFF = 15264,    // [128][4] = 512   fpw1_top @ headw
  F1B_OFF = 15776,    // 512              fpw1_bot @ headw
  B0_OFF  = 16288,    // 128
  BB1_OFF = 16416,    // 128
  WS_END  = 16544
};

// ---------------- prep1: everything derivable from raw inputs (wide) ----------------
__global__ void prep1(
    const float* __restrict__ wq0, const float* __restrict__ wak0, const float* __restrict__ wok0,
    const float* __restrict__ wq1, const float* __restrict__ wak1, const float* __restrict__ wok1,
    const float* __restrict__ wav0, const float* __restrict__ apw0,
    const float* __restrict__ wov0, const float* __restrict__ opw0,
    const float* __restrict__ wav1, const float* __restrict__ apw1,
    const float* __restrict__ wov1, const float* __restrict__ opw1,
    const float* __restrict__ fpw1, const float* __restrict__ headw,
    const float* __restrict__ fpw0,
    const float* __restrict__ fpb0, const float* __restrict__ apb0, const float* __restrict__ opb0,
    const float* __restrict__ fpb1, const float* __restrict__ apb1, const float* __restrict__ opb1,
    float* __restrict__ ws)
{
  int gid = blockIdx.x * NTH + threadIdx.x;
  if (gid < 608) {                                      // WQ0[h][r][j]
    int j = gid & 7, r = (gid >> 3) % 19, h = gid / 152;
    const float* a = wq0 + r * 512 + h * 128;
    const float* b = ((j < 6) ? (wak0 + j * 512) : (wok0 + (j - 6) * 512)) + h * 128;
    float acc = 0.f;
    for (int c = 0; c < 128; c++) acc += a[c] * b[c];
    ws[WQ0_OFF + gid] = acc;
  } else if (gid < 4704) {                              // WQ1[h][cc][j]
    int idx = gid - 608;
    int j = idx & 7, cc = (idx >> 3) & 127, h = idx >> 10;
    const float* a = wq1 + cc * 512 + h * 128;
    const float* b = ((j < 6) ? (wak1 + j * 512) : (wok1 + (j - 6) * 512)) + h * 128;
    float acc = 0.f;
    for (int c = 0; c < 128; c++) acc += a[c] * b[c];
    ws[WQ1_OFF + idx] = acc;
  } else if (gid < 8288) {                              // P_a0[h][i][t]
    int idx = gid - 4704;
    int t = idx & 127, i = (idx >> 7) % 7, h = idx / 896;
    const float* w = wav0 + i * 512 + h * 128;
    const float* p = apw0 + (h * 128) * 128 + t;
    float acc = 0.f;
    for (int c = 0; c < 128; c++) acc += w[c] * p[c * 128];
    ws[PA0_OFF + idx] = acc;
  } else if (gid < 9312) {                              // P_o0[h][i][t]
    int idx = gid - 8288;
    int t = idx & 127, i = (idx >> 7) & 1, h = idx >> 8;
    const float* w = wov0 + i * 512 + h * 128;
    const float* p = opw0 + (h * 128) * 128 + t;
    float acc = 0.f;
    for (int c = 0; c < 128; c++) acc += w[c] * p[c * 128];
    ws[PO0_OFF + idx] = acc;
  } else if (gid < 12896) {                             // P_a1
    int idx = gid - 9312;
    int t = idx & 127, i = (idx >> 7) % 7, h = idx / 896;
    const float* w = wav1 + i * 512 + h * 128;
    const float* p = apw1 + (h * 128) * 128 + t;
    float acc = 0.f;
    for (int c = 0; c < 128; c++) acc += w[c] * p[c * 128];
    ws[PA1_OFF + idx] = acc;
  } else if (gid < 13920) {                             // P_o1
    int idx = gid - 12896;
    int t = idx & 127, i = (idx >> 7) & 1, h = idx >> 8;
    const float* w = wov1 + i * 512 + h * 128;
    const float* p = opw1 + (h * 128) * 128 + t;
    float acc = 0.f;
    for (int c = 0; c < 128; c++) acc += w[c] * p[c * 128];
    ws[PO1_OFF + idx] = acc;
  } else if (gid < 14432) {                             // F1T[i][o]
    int idx = gid - 13920;
    int o2 = idx & 3, i = idx >> 2;
    float acc = 0.f;
    for (int j = 0; j < 128; j++) acc += fpw1[i * 128 + j] * headw[j * 4 + o2];
    ws[F1T_OFF + idx] = acc;
  } else if (gid < 14944) {                             // F1B[i][o]
    int idx = gid - 14432;
    int o2 = idx & 3, i = idx >> 2;
    float acc = 0.f;
    for (int j = 0; j < 128; j++) acc += fpw1[(128 + i) * 128 + j] * headw[j * 4 + o2];
    ws[F1B_OFF + idx] = acc;
  } else if (gid < 15072) {                             // B0[j]
    int j = gid - 14944;
    float acc = fpb0[j];
    for (int c = 0; c < 128; c++)
      acc += apb0[c] * fpw0[c * 128 + j] + opb0[c] * fpw0[(128 + c) * 128 + j];
    ws[B0_OFF + j] = acc;
  } else if (gid < 15200) {                             // bb1[j]
    int j = gid - 15072;
    float acc = fpb1[j];
    for (int c = 0; c < 128; c++)
      acc += apb1[c] * fpw1[c * 128 + j] + opb1[c] * fpw1[(128 + c) * 128 + j];
    ws[BB1_OFF + j] = acc;
  }
}

// ---------------- prep_late: fused prep2+prep3 ----------------
// Blocks 0..35: block t computes AO0 row t (128 dots) into LDS, then M[t][0..32).
// Block 36: AO1 (144), TB (32), B1H (4).  AO0 never touches global memory.
__global__ __launch_bounds__(NTH) void prep_late(
    const float* __restrict__ fpw0, const float* __restrict__ headw,
    const float* __restrict__ headb, float* __restrict__ ws)
{
  const int b = blockIdx.x;
  const int tid = threadIdx.x;
  if (b < 36) {
    __shared__ float sAO0[128];
    const int t = b, h = t / 9, i = t % 9;
    if (tid < 128) {
      float acc = 0.f;
      if (i < 7) {
        const float* P = ws + PA0_OFF + (h * 7 + i) * 128;
        for (int u = 0; u < 128; u++) acc += P[u] * fpw0[u * 128 + tid];
      } else {
        const float* P = ws + PO0_OFF + (h * 2 + (i - 7)) * 128;
        for (int u = 0; u < 128; u++) acc += P[u] * fpw0[(128 + u) * 128 + tid];
      }
      sAO0[tid] = acc;
    }
    __syncthreads();
    if (tid < 32) {                                     // M[t][h2*8+j2]
      const int h2 = tid >> 3, j2 = tid & 7;
      float acc = 0.f;
      const float* W = ws + WQ1_OFF + h2 * 1024 + j2;
      for (int c = 0; c < 128; c++) acc += sAO0[c] * W[c * 8];
      ws[M_OFF + t * 32 + tid] = acc;
    }
  } else {
    if (tid < 144) {                                    // AO1[h][i][o]
      const int o2 = tid & 3, i = (tid >> 2) % 9, h = tid / 36;
      float acc = 0.f;
      if (i < 7) {
        const float* P = ws + PA1_OFF + (h * 7 + i) * 128;
        for (int u = 0; u < 128; u++) acc += P[u] * ws[F1T_OFF + u * 4 + o2];
      } else {
        const float* P = ws + PO1_OFF + (h * 2 + (i - 7)) * 128;
        for (int u = 0; u < 128; u++) acc += P[u] * ws[F1B_OFF + u * 4 + o2];
      }
      ws[AO1_OFF + tid] = acc;
    } else if (tid < 176) {                             // TB[h][j]
      const int idx = tid - 144;
      const int j = idx & 7, h = idx >> 3;
      float acc = 0.f;
      for (int cc = 0; cc < 128; cc++)
        acc += ws[B0_OFF + cc] * ws[WQ1_OFF + h * 1024 + cc * 8 + j];
      ws[TB_OFF + idx] = acc;
    } else if (tid < 180) {                             // B1H[o]
      const int o2 = tid - 176;
      float acc = headb[o2];
      for (int j = 0; j < 128; j++) acc += ws[BB1_OFF + j] * headw[j * 4 + o2];
      ws[B1H_OFF + o2] = acc;
    }
  }
}

// ---------------- main: 1 thread/sample; wave-uniform table reads (scalar pipe) ----------------
__global__ __launch_bounds__(NTH) void actor_main(
    const float* __restrict__ obs, const float* __restrict__ ws,
    const float* __restrict__ pca0, const float* __restrict__ pco0,
    const float* __restrict__ pca1, const float* __restrict__ pco1,
    float* __restrict__ out, int n)
{
  const int gid = blockIdx.x * NTH + threadIdx.x;
  if (gid >= n) return;

  // All tbl[] indices below are compile-time constants -> wave-uniform
  // addresses -> scalar-pipe s_load; table (7.8 KB) stays L1/K$-resident.
  const v4f* __restrict__ tbl = (const v4f*)ws;

  // ---- per-lane obs load (37 contiguous floats) ----
  float o[37];
  {
    const float* op = obs + (size_t)gid * 37;
#pragma unroll
    for (int i = 0; i < 37; i++) o[i] = op[i];
  }
  const float scale = 0.17677669529663687f;   // 1/sqrt(32)

  // ---- unpack features ----
  float qf[19];
#pragma unroll
  for (int i = 0; i < 12; i++) qf[i] = o[i];
#pragma unroll
  for (int i = 0; i < 7; i++) qf[12 + i] = o[30 + i];
  float nb[2][6];
#pragma unroll
  for (int k2 = 0; k2 < 2; k2++)
#pragma unroll
    for (int i = 0; i < 6; i++) nb[k2][i] = o[12 + 6 * k2 + i];
  const float nbv6[2] = { o[24], o[25] };
  const float obf[2][2] = { { o[26], o[27] }, { o[28], o[29] } };
  const float ax = o[0], ay = o[1];

  // ---- distances & decay weights ----
  float dista[2], disto[2];
#pragma unroll
  for (int k2 = 0; k2 < 2; k2++) {
    float dx = ax - nb[k2][0], dy = ay - nb[k2][1];
    dista[k2] = sqrtf(dx * dx + dy * dy);
    float ex = ax - obf[k2][0], ey = ay - obf[k2][1];
    disto[k2] = sqrtf(ex * ex + ey * ey);
  }
  const float ca0 = pca0[0], co0 = pco0[0], ca1 = pca1[0], co1 = pco1[0];
  float dwa0[2], dwo0[2], dwa1[2], dwo1[2];
#pragma unroll
  for (int k2 = 0; k2 < 2; k2++) {
    dwa0[k2] = __expf(-ca0 * dista[k2]);
    dwo0[k2] = __expf(-co0 * disto[k2]);
    dwa1[k2] = __expf(-ca1 * dista[k2]);
    dwo1[k2] = __expf(-co1 * disto[k2]);
  }

  // ---- layer 0 query fold: t0v[h*2+half] (packed) ----
  v4f t0v[8];
#pragma unroll
  for (int z = 0; z < 8; z++) t0v[z] = (v4f)0.f;
#pragma unroll
  for (int h = 0; h < 4; h++) {
#pragma unroll
    for (int r = 0; r < 19; r++) {
      float q = qf[r];
      t0v[h * 2 + 0] += tbl[(h * 19 + r) * 2 + 0] * q;
      t0v[h * 2 + 1] += tbl[(h * 19 + r) * 2 + 1] * q;
    }
  }

  // ---- layer 0 attention -> weighted features wff[36] (t = h*9+i) ----
  float wff[36];
#pragma unroll
  for (int h = 0; h < 4; h++) {
    float la[2], lo[2];
#pragma unroll
    for (int k2 = 0; k2 < 2; k2++) {
      float da = t0v[h*2][0]*nb[k2][0] + t0v[h*2][1]*nb[k2][1] + t0v[h*2][2]*nb[k2][2]
               + t0v[h*2][3]*nb[k2][3] + t0v[h*2+1][0]*nb[k2][4] + t0v[h*2+1][1]*nb[k2][5];
      la[k2] = da * scale * dwa0[k2];
      float dof = t0v[h*2+1][2]*obf[k2][0] + t0v[h*2+1][3]*obf[k2][1];
      lo[k2] = dof * scale * dwo0[k2];
    }
    float e  = __expf(la[1] - la[0]); float aa1 = e  / (1.f + e);  float aa0 = 1.f - aa1;
    float eo = __expf(lo[1] - lo[0]); float bo1 = eo / (1.f + eo); float bo0 = 1.f - bo1;
#pragma unroll
    for (int i = 0; i < 6; i++) wff[h * 9 + i] = aa0 * nb[0][i] + aa1 * nb[1][i];
    wff[h * 9 + 6] = aa0 * nbv6[0] + aa1 * nbv6[1];
    wff[h * 9 + 7] = bo0 * obf[0][0] + bo1 * obf[1][0];
    wff[h * 9 + 8] = bo0 * obf[0][1] + bo1 * obf[1][1];
  }

  // ---- layer 1 query fold via M: t1v = TB + wff @ M (packed) ----
  v4f t1v[8];
#pragma unroll
  for (int q = 0; q < 8; q++) t1v[q] = tbl[440 + q];
#pragma unroll
  for (int t = 0; t < 36; t++) {
    float f = wff[t];
#pragma unroll
    for (int q = 0; q < 8; q++)
      t1v[q] += tbl[152 + t * 8 + q] * f;
  }

  // ---- layer 1 attention ----
  float wf1f[36];
#pragma unroll
  for (int h = 0; h < 4; h++) {
    float la[2], lo[2];
#pragma unroll
    for (int k2 = 0; k2 < 2; k2++) {
      float da = t1v[h*2][0]*nb[k2][0] + t1v[h*2][1]*nb[k2][1] + t1v[h*2][2]*nb[k2][2]
               + t1v[h*2][3]*nb[k2][3] + t1v[h*2+1][0]*nb[k2][4] + t1v[h*2+1][1]*nb[k2][5];
      la[k2] = da * scale * dwa1[k2];
      float dof = t1v[h*2+1][2]*obf[k2][0] + t1v[h*2+1][3]*obf[k2][1];
      lo[k2] = dof * scale * dwo1[k2];
    }
    float e  = __expf(la[1] - la[0]); float aa1 = e  / (1.f + e);  float aa0 = 1.f - aa1;
    float eo = __expf(lo[1] - lo[0]); float bo1 = eo / (1.f + eo); float bo0 = 1.f - bo1;
#pragma unroll
    for (int i = 0; i < 6; i++) wf1f[h * 9 + i] = aa0 * nb[0][i] + aa1 * nb[1][i];
    wf1f[h * 9 + 6] = aa0 * nbv6[0] + aa1 * nbv6[1];
    wf1f[h * 9 + 7] = bo0 * obf[0][0] + bo1 * obf[1][0];
    wf1f[h * 9 + 8] = bo0 * obf[0][1] + bo1 * obf[1][1];
  }

  // ---- output: B1H + wf1f @ AO1 (packed) ----
  v4f acc = tbl[484];
#pragma unroll
  for (int t = 0; t < 36; t++)
    acc += tbl[448 + t] * wf1f[t];
  ((v4f*)out)[gid] = acc;
}

extern "C" void kernel_launch(void* const* d_in, const int* in_sizes, int n_in,
                              void* d_out, int out_size, void* d_ws, size_t ws_size,
                              hipStream_t stream)
{
  const float* obs  = (const float*)d_in[0];
  const float* wq0  = (const float*)d_in[1];
  const float* wak0 = (const float*)d_in[2];
  const float* wav0 = (const float*)d_in[3];
  const float* wok0 = (const float*)d_in[4];
  const float* wov0 = (const float*)d_in[5];
  const float* apw0 = (const float*)d_in[6];
  const float* apb0 = (const float*)d_in[7];
  const float* opw0 = (const float*)d_in[8];
  const float* opb0 = (const float*)d_in[9];
  const float* fpw0 = (const float*)d_in[10];
  const float* fpb0 = (const float*)d_in[11];
  const float* ca0  = (const float*)d_in[12];
  const float* co0  = (const float*)d_in[13];
  const float* wq1  = (const float*)d_in[14];
  const float* wak1 = (const float*)d_in[15];
  const float* wav1 = (const float*)d_in[16];
  const float* wok1 = (const float*)d_in[17];
  const float* wov1 = (const float*)d_in[18];
  const float* apw1 = (const float*)d_in[19];
  const float* apb1 = (const float*)d_in[20];
  const float* opw1 = (const float*)d_in[21];
  const float* opb1 = (const float*)d_in[22];
  const float* fpw1 = (const float*)d_in[23];
  const float* fpb1 = (const float*)d_in[24];
  const float* ca1  = (const float*)d_in[25];
  const float* co1  = (const float*)d_in[26];
  const float* headw = (const float*)d_in[27];
  const float* headb = (const float*)d_in[28];
  float* ws = (float*)d_ws;
  int n = in_sizes[0] / 37;

  prep1<<<(15200 + NTH - 1) / NTH, NTH, 0, stream>>>(
      wq0, wak0, wok0, wq1, wak1, wok1,
      wav0, apw0, wov0, opw0, wav1, apw1, wov1, opw1,
      fpw1, headw, fpw0, fpb0, apb0, opb0, fpb1, apb1, opb1, ws);
  prep_late<<<37, NTH, 0, stream>>>(fpw0, headw, headb, ws);
  actor_main<<<(n + NTH - 1) / NTH, NTH, 0, stream>>>(
      obs, ws, ca0, co0, ca1, co1, (float*)d_out, n);
}